// Round 5
// baseline (312.519 us; speedup 1.0000x reference)
//
#include <hip/hip_runtime.h>
#include <math.h>

typedef _Float16 half_t;
typedef _Float16 halfx8 __attribute__((ext_vector_type(8)));
typedef _Float16 halfx4 __attribute__((ext_vector_type(4)));
typedef float floatx4 __attribute__((ext_vector_type(4)));
typedef float floatx16 __attribute__((ext_vector_type(16)));
typedef unsigned int uintx2 __attribute__((ext_vector_type(2)));
typedef unsigned int uintx4 __attribute__((ext_vector_type(4)));

typedef __attribute__((address_space(3))) void lds_t;
typedef const __attribute__((address_space(1))) void gmem_t;

static constexpr int kB = 2;
static constexpr int kLD = 2048;
static constexpr int kLM = 2048;
static constexpr int kD = 1024;
static constexpr int kH = 16;
static constexpr int kDH = 64;

__device__ __forceinline__ float exp2_fast(float x) {
#if __has_builtin(__builtin_amdgcn_exp2f)
  return __builtin_amdgcn_exp2f(x);
#else
  return exp2f(x);
#endif
}

// ---------------------------------------------------------------------------
// 1) f32 -> f16 conversion of X_dec, X_enc, Wq, Wk, Wv; plus attention-mask
//    int -> additive f32 (-1e30 / 0) table.
// ---------------------------------------------------------------------------
__global__ __launch_bounds__(256) void convert_all(
    const float* __restrict__ s0, const float* __restrict__ s1,
    const float* __restrict__ s2, const float* __restrict__ s3,
    const float* __restrict__ s4, const int* __restrict__ am,
    half_t* __restrict__ d0, half_t* __restrict__ d1,
    half_t* __restrict__ d2, half_t* __restrict__ d3, half_t* __restrict__ d4,
    float* __restrict__ maskf)
{
  const size_t N0 = (size_t)kB * kLD * kD;
  const size_t N1 = N0 + (size_t)kB * kLM * kD;
  const size_t N2 = N1 + (size_t)kD * kD;
  const size_t N3 = N2 + (size_t)kD * kD;
  const size_t N4 = N3 + (size_t)kD * kD;
  const size_t N5 = N4 + (size_t)kB * kLM;
  size_t idx = ((size_t)blockIdx.x * blockDim.x + threadIdx.x) * 4;
  if (idx >= N5) return;
  if (idx >= N4) {  // attention mask -> additive f32
    const size_t off = idx - N4;
    int4 m = *(const int4*)(am + off);
    float4 o;
    o.x = m.x ? 0.0f : -1e30f;
    o.y = m.y ? 0.0f : -1e30f;
    o.z = m.z ? 0.0f : -1e30f;
    o.w = m.w ? 0.0f : -1e30f;
    *(float4*)(maskf + off) = o;
    return;
  }
  const float* s; half_t* d; size_t off;
  if (idx < N0)      { s = s0; d = d0; off = idx; }
  else if (idx < N1) { s = s1; d = d1; off = idx - N0; }
  else if (idx < N2) { s = s2; d = d2; off = idx - N1; }
  else if (idx < N3) { s = s3; d = d3; off = idx - N2; }
  else               { s = s4; d = d4; off = idx - N3; }
  float4 v = *(const float4*)(s + off);
  halfx4 hv;
  hv[0] = (half_t)v.x; hv[1] = (half_t)v.y; hv[2] = (half_t)v.z; hv[3] = (half_t)v.w;
  *(halfx4*)(d + off) = hv;
}

// ---------------------------------------------------------------------------
// 2) Fused QKV projection GEMM (m97 structure). Q scaled by 0.125*log2(e) so
//    attention softmax runs in exp2 domain.
// ---------------------------------------------------------------------------
__global__ __launch_bounds__(256, 2) void qkv_gemm(
    const half_t* __restrict__ xdec, const half_t* __restrict__ xenc,
    const half_t* __restrict__ wq, const half_t* __restrict__ wk,
    const half_t* __restrict__ wv,
    const float* __restrict__ bq, const float* __restrict__ bk,
    const float* __restrict__ bv,
    half_t* __restrict__ qbuf, half_t* __restrict__ kbuf,
    half_t* __restrict__ vtbuf)
{
  const int mode = blockIdx.z;
  const half_t* Ag = (mode == 0) ? xdec : xenc;
  const half_t* Bg = (mode == 0) ? wq : (mode == 1) ? wk : wv;
  const float* bias = (mode == 0) ? bq : (mode == 1) ? bk : bv;

  __shared__ alignas(16) half_t Alds[128 * 64];
  __shared__ alignas(16) half_t Blds[128 * 64];

  const int m0 = blockIdx.x * 128;
  const int n0 = blockIdx.y * 128;
  const int tid = threadIdx.x;
  const int lane = tid & 63;
  const int wid = tid >> 6;
  const int wr = wid >> 1, wc = wid & 1;
  const int l15 = lane & 15, lhi = lane >> 4;

  floatx4 acc[4][4] = {};

  for (int k0 = 0; k0 < kD; k0 += 64) {
    __syncthreads();
#pragma unroll
    for (int i = 0; i < 4; ++i) {
      const int ob = wid * 4096 + i * 1024;
      const int lo = ob + lane * 16;
      const int row = lo >> 7;
      const int colh = (lo & 127) >> 1;
      const half_t* ga = Ag + (size_t)(m0 + row) * kD + k0 + colh;
      const half_t* gb = Bg + (size_t)(n0 + row) * kD + k0 + colh;
      __builtin_amdgcn_global_load_lds((gmem_t*)ga, (lds_t*)((char*)Alds + ob), 16, 0, 0);
      __builtin_amdgcn_global_load_lds((gmem_t*)gb, (lds_t*)((char*)Blds + ob), 16, 0, 0);
    }
    __syncthreads();

#pragma unroll
    for (int ks = 0; ks < 2; ++ks) {
      halfx8 af[4], bf[4];
#pragma unroll
      for (int mt = 0; mt < 4; ++mt)
        af[mt] = *(const halfx8*)(Alds + (wr * 64 + mt * 16 + l15) * 64 + ks * 32 + lhi * 8);
#pragma unroll
      for (int nt = 0; nt < 4; ++nt)
        bf[nt] = *(const halfx8*)(Blds + (wc * 64 + nt * 16 + l15) * 64 + ks * 32 + lhi * 8);
#pragma unroll
      for (int mt = 0; mt < 4; ++mt)
#pragma unroll
        for (int nt = 0; nt < 4; ++nt)
          acc[mt][nt] = __builtin_amdgcn_mfma_f32_16x16x32_f16(af[mt], bf[nt], acc[mt][nt], 0, 0, 0);
    }
  }

#pragma unroll
  for (int nt = 0; nt < 4; ++nt) {
    const int n = n0 + wc * 64 + nt * 16 + l15;
    const float bb = bias[n];
    const int h = n >> 6, dv = n & 63;
#pragma unroll
    for (int mt = 0; mt < 4; ++mt) {
#pragma unroll
      for (int r = 0; r < 4; ++r) {
        const int m = m0 + wr * 64 + mt * 16 + lhi * 4 + r;
        const int b = m >> 11, rowl = m & 2047;
        float v = acc[mt][nt][r] + bb;
        if (mode == 0) {
          v *= 0.18033688011112042f;  // (1/sqrt(64)) * log2(e)
          qbuf[((size_t)(b * kH + h) * kLD + rowl) * kDH + dv] = (half_t)v;
        } else if (mode == 1) {
          kbuf[((size_t)(b * kH + h) * kLM + rowl) * kDH + dv] = (half_t)v;
        } else {
          vtbuf[((size_t)(b * kH + h) * kDH + dv) * kLM + rowl] = (half_t)v;
        }
      }
    }
  }
}

// ---------------------------------------------------------------------------
// 3) Flash attention with in-block KV-split.
//    Block = (b,h, 64 q-rows), 256 threads = 2 wave-pairs; pair p covers
//    kv [p*1024, (p+1)*1024). Issue-early reg staging (T14), tree
//    reductions, defer-max (T13), in-register softmax via swapped QK^T,
//    cvt_pkrtz+permlane P-pack, end-of-block partial merge through LDS.
// ---------------------------------------------------------------------------
__global__ __launch_bounds__(256, 4) void attn_kernel(
    const half_t* __restrict__ qbuf, const half_t* __restrict__ kbuf,
    const half_t* __restrict__ vtbuf, const float* __restrict__ maskf,
    const int* __restrict__ hmask, float* __restrict__ out)
{
  // XCD swizzle: 128 consecutive blocks (4 bh) per XCD
  const int x = blockIdx.x;
  const int ordered = (x & 7) * 128 + (x >> 3);
  const int bh = ordered >> 5, qt = ordered & 31;
  const int b = bh >> 4, h = bh & 15;

  const int tid = threadIdx.x;
  const int lane = tid & 63;
  const int wid = tid >> 6;
  const int p = wid >> 1;    // kv-half (0/1)
  const int qw = wid & 1;    // 32-q group within the 64-q block
  const int ql = lane & 31;
  const int hi = lane >> 5;
  const int tid_p = tid & 127;

  __shared__ alignas(16) char smem[33 * 1024];
  half_t* Klds = (half_t*)(smem + p * 16384);          // [64 kv][64 d], swz
  half_t* Vlds = (half_t*)(smem + p * 16384 + 8192);   // [64 dv][64 kv], swz
  float* mlds = (float*)(smem + 32768);                // [2][m|l][64 q]

  const half_t* kbase = kbuf + (size_t)bh * (kLM * kDH) + (size_t)p * 1024 * kDH;
  const half_t* vtbase = vtbuf + (size_t)bh * (kDH * kLM) + p * 1024;
  const float* mbase = maskf + b * kLM + p * 1024;

  const int qg = qt * 64 + qw * 32 + ql;  // global q row
  halfx8 qf[4];
#pragma unroll
  for (int ks = 0; ks < 4; ++ks)
    qf[ks] = *(const halfx8*)(qbuf + ((size_t)bh * kLD + qg) * kDH + ks * 16 + hi * 8);

  // prologue: stage tile 0 into regs
  int4 kreg[4], vreg[4];
#pragma unroll
  for (int i = 0; i < 4; ++i) {
    const int c = i * 128 + tid_p;
    const int row = c >> 3, c16 = c & 7;
    kreg[i] = *(const int4*)(kbase + (size_t)row * kDH + c16 * 8);
    vreg[i] = *(const int4*)(vtbase + (size_t)row * kLM + c16 * 8);
  }

  floatx16 ctx0 = {}, ctx1 = {};
  float m_run = -1e30f, l_run = 0.0f;

#pragma unroll 1
  for (int t = 0; t < 16; ++t) {
    const int kv0 = t * 64;
    __syncthreads();  // prior tile's LDS reads done
#pragma unroll
    for (int i = 0; i < 4; ++i) {
      const int c = i * 128 + tid_p;
      const int row = c >> 3, c16 = c & 7;
      const int off = (row * 128 + c16 * 16) ^ ((row & 7) << 4);
      *(int4*)((char*)Klds + off) = kreg[i];
      *(int4*)((char*)Vlds + off) = vreg[i];
    }
    if (t < 15) {  // T14: issue next tile's loads before compute
      const int kvn = kv0 + 64;
#pragma unroll
      for (int i = 0; i < 4; ++i) {
        const int c = i * 128 + tid_p;
        const int row = c >> 3, c16 = c & 7;
        kreg[i] = *(const int4*)(kbase + (size_t)(kvn + row) * kDH + c16 * 8);
        vreg[i] = *(const int4*)(vtbase + (size_t)row * kLM + kvn + c16 * 8);
      }
    }
    __syncthreads();  // LDS tile visible

    // S accumulators init from additive mask (folds mask add into MFMA C-in)
    floatx16 S0, S1;
#pragma unroll
    for (int g = 0; g < 4; ++g) {
      float4 a0 = *(const float4*)(mbase + kv0 + g * 8 + hi * 4);
      float4 a1 = *(const float4*)(mbase + kv0 + 32 + g * 8 + hi * 4);
      S0[g * 4 + 0] = a0.x; S0[g * 4 + 1] = a0.y; S0[g * 4 + 2] = a0.z; S0[g * 4 + 3] = a0.w;
      S1[g * 4 + 0] = a1.x; S1[g * 4 + 1] = a1.y; S1[g * 4 + 2] = a1.z; S1[g * 4 + 3] = a1.w;
    }

    // S^T = K · Q^T (swapped operands)
#pragma unroll
    for (int ks = 0; ks < 4; ++ks) {
      const int off0 = (ql * 128 + ks * 32 + hi * 16) ^ ((ql & 7) << 4);
      halfx8 kf0 = *(const halfx8*)((const char*)Klds + off0);
      S0 = __builtin_amdgcn_mfma_f32_32x32x16_f16(kf0, qf[ks], S0, 0, 0, 0);
      const int off1 = ((32 + ql) * 128 + ks * 32 + hi * 16) ^ ((ql & 7) << 4);
      halfx8 kf1 = *(const halfx8*)((const char*)Klds + off1);
      S1 = __builtin_amdgcn_mfma_f32_32x32x16_f16(kf1, qf[ks], S1, 0, 0, 0);
    }

    // tree max (depth ~5)
    float mx8[8];
#pragma unroll
    for (int i = 0; i < 8; ++i)
      mx8[i] = fmaxf(fmaxf(S0[i], S0[i + 8]), fmaxf(S1[i], S1[i + 8]));
#pragma unroll
    for (int i = 0; i < 4; ++i) mx8[i] = fmaxf(mx8[i], mx8[i + 4]);
    float mx = fmaxf(fmaxf(mx8[0], mx8[1]), fmaxf(mx8[2], mx8[3]));
    mx = fmaxf(mx, __shfl_xor(mx, 32));

    // T13 defer-max: rescale only when max grew past threshold (exp2 units)
    if (!__all(mx <= m_run + 8.0f)) {
      const float mn = fmaxf(m_run, mx);
      const float sc = exp2_fast(m_run - mn);
      m_run = mn;
      l_run *= sc;
#pragma unroll
      for (int i = 0; i < 16; ++i) { ctx0[i] *= sc; ctx1[i] *= sc; }
    }

    // P = exp2(S - m), tree sum
#pragma unroll
    for (int i = 0; i < 16; ++i) {
      S0[i] = exp2_fast(S0[i] - m_run);
      S1[i] = exp2_fast(S1[i] - m_run);
    }
    float sm8[8];
#pragma unroll
    for (int i = 0; i < 8; ++i)
      sm8[i] = (S0[i] + S0[i + 8]) + (S1[i] + S1[i + 8]);
#pragma unroll
    for (int i = 0; i < 4; ++i) sm8[i] += sm8[i + 4];
    float ps = (sm8[0] + sm8[1]) + (sm8[2] + sm8[3]);
    ps += __shfl_xor(ps, 32);
    l_run += ps;

    // pack P^T into PV B-fragments: cvt_pkrtz + permlane32_swap
    halfx8 pb[4];
#pragma unroll
    for (int sl = 0; sl < 4; ++sl) {
      const floatx16& P = (sl < 2) ? S0 : S1;
      const int rA = (sl & 1) * 8;
      unsigned wa = __builtin_bit_cast(unsigned, __builtin_amdgcn_cvt_pkrtz(P[rA + 0], P[rA + 1]));
      unsigned wb = __builtin_bit_cast(unsigned, __builtin_amdgcn_cvt_pkrtz(P[rA + 2], P[rA + 3]));
      unsigned wc = __builtin_bit_cast(unsigned, __builtin_amdgcn_cvt_pkrtz(P[rA + 4], P[rA + 5]));
      unsigned wd = __builtin_bit_cast(unsigned, __builtin_amdgcn_cvt_pkrtz(P[rA + 6], P[rA + 7]));
      uintx2 u1 = __builtin_amdgcn_permlane32_swap(wa, wc, false, false);
      uintx2 u2 = __builtin_amdgcn_permlane32_swap(wb, wd, false, false);
      uintx4 u;
      u[0] = u1[0]; u[1] = u2[0]; u[2] = u1[1]; u[3] = u2[1];
      pb[sl] = __builtin_bit_cast(halfx8, u);
    }

    // ctx^T += V^T · P^T
#pragma unroll
    for (int sl = 0; sl < 4; ++sl) {
      const int off0 = (ql * 128 + sl * 32 + hi * 16) ^ ((ql & 7) << 4);
      halfx8 vf0 = *(const halfx8*)((const char*)Vlds + off0);
      ctx0 = __builtin_amdgcn_mfma_f32_32x32x16_f16(vf0, pb[sl], ctx0, 0, 0, 0);
      const int off1 = ((32 + ql) * 128 + sl * 32 + hi * 16) ^ ((ql & 7) << 4);
      halfx8 vf1 = *(const halfx8*)((const char*)Vlds + off1);
      ctx1 = __builtin_amdgcn_mfma_f32_32x32x16_f16(vf1, pb[sl], ctx1, 0, 0, 0);
    }
  }

  // ---- in-block combine of the two kv-halves ----
  __syncthreads();  // all KV LDS reads done; overlay O on KV space
  {
    float* Op = (float*)(smem + p * 16384);  // [64 q][64 dv], swz
    const int q_local = qw * 32 + ql;
#pragma unroll
    for (int g = 0; g < 4; ++g) {
#pragma unroll
      for (int pr = 0; pr < 2; ++pr) {
        const int r = g * 4 + pr * 2;
        const int dv0 = pr * 2 + 8 * g + 4 * hi;
        const int off0 = (q_local * 256 + dv0 * 4) ^ ((q_local & 7) << 4);
        *(float2*)((char*)Op + off0) = make_float2(ctx0[r], ctx0[r + 1]);
        const int off1 = (q_local * 256 + (dv0 + 32) * 4) ^ ((q_local & 7) << 4);
        *(float2*)((char*)Op + off1) = make_float2(ctx1[r], ctx1[r + 1]);
      }
    }
    if (hi == 0) {
      mlds[p * 128 + q_local] = m_run;
      mlds[p * 128 + 64 + q_local] = l_run;
    }
  }
  __syncthreads();

#pragma unroll
  for (int it = 0; it < 4; ++it) {
    const int idx = it * 256 + tid;
    const int q = idx >> 4, c4 = idx & 15;
    const int off = (q * 256 + c4 * 16) ^ ((q & 7) << 4);
    float4 o0 = *(const float4*)(smem + off);
    float4 o1 = *(const float4*)(smem + 16384 + off);
    const float m0 = mlds[q], l0 = mlds[64 + q];
    const float m1 = mlds[128 + q], l1 = mlds[192 + q];
    const float mm = fmaxf(m0, m1);
    float w0 = exp2_fast(m0 - mm), w1 = exp2_fast(m1 - mm);
    const int qglob = qt * 64 + q;
    const float inv = (hmask[b * kLD + qglob] ? 0.0f : 1.0f) / (l0 * w0 + l1 * w1);
    w0 *= inv; w1 *= inv;
    float4 o;
    o.x = o0.x * w0 + o1.x * w1;
    o.y = o0.y * w0 + o1.y * w1;
    o.z = o0.z * w0 + o1.z * w1;
    o.w = o0.w * w0 + o1.w * w1;
    *(float4*)(out + (((size_t)(b * kLD + qglob)) << 10) + h * 64 + c4 * 4) = o;
  }
}

// ---------------------------------------------------------------------------
extern "C" void kernel_launch(void* const* d_in, const int* in_sizes, int n_in,
                              void* d_out, int out_size, void* d_ws, size_t ws_size,
                              hipStream_t stream)
{
  const float* hs   = (const float*)d_in[0];
  const float* ehs  = (const float*)d_in[1];
  const int*   am   = (const int*)d_in[2];
  const int*   hm   = (const int*)d_in[3];
  const float* Wq   = (const float*)d_in[4];
  const float* bq   = (const float*)d_in[5];
  const float* Wk   = (const float*)d_in[6];
  const float* bk   = (const float*)d_in[7];
  const float* Wv   = (const float*)d_in[8];
  const float* bv   = (const float*)d_in[9];
  float* out = (float*)d_out;

  char* ws = (char*)d_ws;
  half_t* xdec_h = (half_t*)(ws);
  half_t* xenc_h = (half_t*)(ws + (8ull << 20));
  half_t* wq_h   = (half_t*)(ws + (16ull << 20));
  half_t* wk_h   = (half_t*)(ws + (18ull << 20));
  half_t* wv_h   = (half_t*)(ws + (20ull << 20));
  half_t* q_buf  = (half_t*)(ws + (22ull << 20));
  half_t* k_buf  = (half_t*)(ws + (30ull << 20));
  half_t* vt_buf = (half_t*)(ws + (38ull << 20));
  float*  maskf  = (float*)(ws + (46ull << 20));

  convert_all<<<11268, 256, 0, stream>>>(hs, ehs, Wq, Wk, Wv, am,
                                         xdec_h, xenc_h, wq_h, wk_h, wv_h, maskf);
  qkv_gemm<<<dim3(32, 8, 3), 256, 0, stream>>>(xdec_h, xenc_h, wq_h, wk_h, wv_h,
                                               bq, bk, bv, q_buf, k_buf, vt_buf);
  attn_kernel<<<1024, 256, 0, stream>>>(q_buf, k_buf, vt_buf, maskf, hm, out);
}

// Round 6
// 213.173 us; speedup vs baseline: 1.4660x; 1.4660x over previous
//
#include <hip/hip_runtime.h>
#include <math.h>

typedef _Float16 half_t;
typedef _Float16 halfx8 __attribute__((ext_vector_type(8)));
typedef _Float16 halfx4 __attribute__((ext_vector_type(4)));
typedef float floatx4 __attribute__((ext_vector_type(4)));
typedef float floatx16 __attribute__((ext_vector_type(16)));
typedef unsigned int uintx2 __attribute__((ext_vector_type(2)));
typedef unsigned int uintx4 __attribute__((ext_vector_type(4)));

typedef __attribute__((address_space(3))) void lds_t;
typedef const __attribute__((address_space(1))) void gmem_t;

static constexpr int kB = 2;
static constexpr int kLD = 2048;
static constexpr int kLM = 2048;
static constexpr int kD = 1024;
static constexpr int kH = 16;
static constexpr int kDH = 64;

__device__ __forceinline__ float exp2_fast(float x) {
#if __has_builtin(__builtin_amdgcn_exp2f)
  return __builtin_amdgcn_exp2f(x);
#else
  return exp2f(x);
#endif
}

// ---------------------------------------------------------------------------
// 1) f32 -> f16 conversion of X_dec, X_enc, Wq, Wk, Wv; plus attention-mask
//    int -> additive f32 (-1e30 / 0) table.
// ---------------------------------------------------------------------------
__global__ __launch_bounds__(256) void convert_all(
    const float* __restrict__ s0, const float* __restrict__ s1,
    const float* __restrict__ s2, const float* __restrict__ s3,
    const float* __restrict__ s4, const int* __restrict__ am,
    half_t* __restrict__ d0, half_t* __restrict__ d1,
    half_t* __restrict__ d2, half_t* __restrict__ d3, half_t* __restrict__ d4,
    float* __restrict__ maskf)
{
  const size_t N0 = (size_t)kB * kLD * kD;
  const size_t N1 = N0 + (size_t)kB * kLM * kD;
  const size_t N2 = N1 + (size_t)kD * kD;
  const size_t N3 = N2 + (size_t)kD * kD;
  const size_t N4 = N3 + (size_t)kD * kD;
  const size_t N5 = N4 + (size_t)kB * kLM;
  size_t idx = ((size_t)blockIdx.x * blockDim.x + threadIdx.x) * 4;
  if (idx >= N5) return;
  if (idx >= N4) {  // attention mask -> additive f32
    const size_t off = idx - N4;
    int4 m = *(const int4*)(am + off);
    float4 o;
    o.x = m.x ? 0.0f : -1e30f;
    o.y = m.y ? 0.0f : -1e30f;
    o.z = m.z ? 0.0f : -1e30f;
    o.w = m.w ? 0.0f : -1e30f;
    *(float4*)(maskf + off) = o;
    return;
  }
  const float* s; half_t* d; size_t off;
  if (idx < N0)      { s = s0; d = d0; off = idx; }
  else if (idx < N1) { s = s1; d = d1; off = idx - N0; }
  else if (idx < N2) { s = s2; d = d2; off = idx - N1; }
  else if (idx < N3) { s = s3; d = d3; off = idx - N2; }
  else               { s = s4; d = d4; off = idx - N3; }
  float4 v = *(const float4*)(s + off);
  halfx4 hv;
  hv[0] = (half_t)v.x; hv[1] = (half_t)v.y; hv[2] = (half_t)v.z; hv[3] = (half_t)v.w;
  *(halfx4*)(d + off) = hv;
}

// ---------------------------------------------------------------------------
// 2) Fused QKV projection GEMM (m97 structure). Q scaled by 0.125*log2(e) so
//    attention softmax runs in exp2 domain.
// ---------------------------------------------------------------------------
__global__ __launch_bounds__(256, 2) void qkv_gemm(
    const half_t* __restrict__ xdec, const half_t* __restrict__ xenc,
    const half_t* __restrict__ wq, const half_t* __restrict__ wk,
    const half_t* __restrict__ wv,
    const float* __restrict__ bq, const float* __restrict__ bk,
    const float* __restrict__ bv,
    half_t* __restrict__ qbuf, half_t* __restrict__ kbuf,
    half_t* __restrict__ vtbuf)
{
  const int mode = blockIdx.z;
  const half_t* Ag = (mode == 0) ? xdec : xenc;
  const half_t* Bg = (mode == 0) ? wq : (mode == 1) ? wk : wv;
  const float* bias = (mode == 0) ? bq : (mode == 1) ? bk : bv;

  __shared__ alignas(16) half_t Alds[128 * 64];
  __shared__ alignas(16) half_t Blds[128 * 64];

  const int m0 = blockIdx.x * 128;
  const int n0 = blockIdx.y * 128;
  const int tid = threadIdx.x;
  const int lane = tid & 63;
  const int wid = tid >> 6;
  const int wr = wid >> 1, wc = wid & 1;
  const int l15 = lane & 15, lhi = lane >> 4;

  floatx4 acc[4][4] = {};

  for (int k0 = 0; k0 < kD; k0 += 64) {
    __syncthreads();
#pragma unroll
    for (int i = 0; i < 4; ++i) {
      const int ob = wid * 4096 + i * 1024;
      const int lo = ob + lane * 16;
      const int row = lo >> 7;
      const int colh = (lo & 127) >> 1;
      const half_t* ga = Ag + (size_t)(m0 + row) * kD + k0 + colh;
      const half_t* gb = Bg + (size_t)(n0 + row) * kD + k0 + colh;
      __builtin_amdgcn_global_load_lds((gmem_t*)ga, (lds_t*)((char*)Alds + ob), 16, 0, 0);
      __builtin_amdgcn_global_load_lds((gmem_t*)gb, (lds_t*)((char*)Blds + ob), 16, 0, 0);
    }
    __syncthreads();

#pragma unroll
    for (int ks = 0; ks < 2; ++ks) {
      halfx8 af[4], bf[4];
#pragma unroll
      for (int mt = 0; mt < 4; ++mt)
        af[mt] = *(const halfx8*)(Alds + (wr * 64 + mt * 16 + l15) * 64 + ks * 32 + lhi * 8);
#pragma unroll
      for (int nt = 0; nt < 4; ++nt)
        bf[nt] = *(const halfx8*)(Blds + (wc * 64 + nt * 16 + l15) * 64 + ks * 32 + lhi * 8);
#pragma unroll
      for (int mt = 0; mt < 4; ++mt)
#pragma unroll
        for (int nt = 0; nt < 4; ++nt)
          acc[mt][nt] = __builtin_amdgcn_mfma_f32_16x16x32_f16(af[mt], bf[nt], acc[mt][nt], 0, 0, 0);
    }
  }

#pragma unroll
  for (int nt = 0; nt < 4; ++nt) {
    const int n = n0 + wc * 64 + nt * 16 + l15;
    const float bb = bias[n];
    const int h = n >> 6, dv = n & 63;
#pragma unroll
    for (int mt = 0; mt < 4; ++mt) {
#pragma unroll
      for (int r = 0; r < 4; ++r) {
        const int m = m0 + wr * 64 + mt * 16 + lhi * 4 + r;
        const int b = m >> 11, rowl = m & 2047;
        float v = acc[mt][nt][r] + bb;
        if (mode == 0) {
          v *= 0.18033688011112042f;  // (1/sqrt(64)) * log2(e)
          qbuf[((size_t)(b * kH + h) * kLD + rowl) * kDH + dv] = (half_t)v;
        } else if (mode == 1) {
          kbuf[((size_t)(b * kH + h) * kLM + rowl) * kDH + dv] = (half_t)v;
        } else {
          vtbuf[((size_t)(b * kH + h) * kDH + dv) * kLM + rowl] = (half_t)v;
        }
      }
    }
  }
}

// ---------------------------------------------------------------------------
// 3) Flash attention with in-block KV-split.
//    Block = (b,h, 64 q-rows), 2 wave-pairs; pair p covers kv [p*1024,
//    (p+1)*1024). K/V staged via global_load_lds w=16 (no staging VGPRs,
//    no spills); XOR swizzle applied on the GLOBAL source address (m173),
//    LDS dest linear, read-side swizzle unchanged. Tree reductions,
//    defer-max (T13), in-register softmax via swapped QK^T,
//    cvt_pkrtz+permlane P-pack, end-of-block partial merge through LDS.
// ---------------------------------------------------------------------------
__global__ __launch_bounds__(256) void attn_kernel(
    const half_t* __restrict__ qbuf, const half_t* __restrict__ kbuf,
    const half_t* __restrict__ vtbuf, const float* __restrict__ maskf,
    const int* __restrict__ hmask, float* __restrict__ out)
{
  // XCD swizzle: 128 consecutive blocks (4 bh) per XCD
  const int x = blockIdx.x;
  const int ordered = (x & 7) * 128 + (x >> 3);
  const int bh = ordered >> 5, qt = ordered & 31;
  const int b = bh >> 4, h = bh & 15;

  const int tid = threadIdx.x;
  const int lane = tid & 63;
  const int wid = tid >> 6;
  const int p = wid >> 1;    // kv-half (0/1)
  const int w = wid & 1;     // wave within pair = q-group = staging half
  const int ql = lane & 31;
  const int hi = lane >> 5;

  __shared__ alignas(16) char smem[33 * 1024];
  half_t* Klds = (half_t*)(smem + p * 16384);          // [64 kv][64 d], swz content
  half_t* Vlds = (half_t*)(smem + p * 16384 + 8192);   // [64 dv][64 kv], swz content
  float* mlds = (float*)(smem + 32768);                // [2][m|l][64 q]

  const half_t* kbase = kbuf + (size_t)bh * (kLM * kDH) + (size_t)p * 1024 * kDH;
  const half_t* vtbase = vtbuf + (size_t)bh * (kDH * kLM) + p * 1024;
  const float* mbase = maskf + b * kLM + p * 1024;

  // per-lane swizzled-source offsets for global_load_lds staging.
  // LDS slot (row, chunk) must hold global chunk (chunk ^ (row&7)); HW writes
  // lane l -> slot (l>>3, l&7), and row&7 == l>>3 for all issues.
  const int lrow = lane >> 3;
  const int lchunk = lane & 7;
  const int xcol = (lchunk ^ lrow) * 8;                  // element offset in row
  const size_t koff = (size_t)(w * 32 + lrow) * kDH + xcol;
  const size_t voff = (size_t)(w * 32 + lrow) * kLM + xcol;

  const int qg = qt * 64 + w * 32 + ql;  // global q row
  halfx8 qf[4];
#pragma unroll
  for (int ks = 0; ks < 4; ++ks)
    qf[ks] = *(const halfx8*)(qbuf + ((size_t)bh * kLD + qg) * kDH + ks * 16 + hi * 8);

  floatx16 ctx0 = {}, ctx1 = {};
  float m_run = -1e30f, l_run = 0.0f;

#pragma unroll 1
  for (int t = 0; t < 16; ++t) {
    const int kv0 = t * 64;
    __syncthreads();  // prior tile's LDS reads done
#pragma unroll
    for (int i = 0; i < 4; ++i) {
      // K: rows [w*32+i*8, +8), 64 halves/row; V^T: rows = dv, same pattern
      __builtin_amdgcn_global_load_lds(
          (gmem_t*)(kbase + (size_t)kv0 * kDH + koff + i * 8 * kDH),
          (lds_t*)((char*)Klds + w * 4096 + i * 1024), 16, 0, 0);
      __builtin_amdgcn_global_load_lds(
          (gmem_t*)(vtbase + kv0 + voff + (size_t)i * 8 * kLM),
          (lds_t*)((char*)Vlds + w * 4096 + i * 1024), 16, 0, 0);
    }
    __syncthreads();  // drains vmcnt: tile visible

    // S accumulators init from additive mask (folds mask add into MFMA C-in)
    floatx16 S0, S1;
#pragma unroll
    for (int g = 0; g < 4; ++g) {
      float4 a0 = *(const float4*)(mbase + kv0 + g * 8 + hi * 4);
      float4 a1 = *(const float4*)(mbase + kv0 + 32 + g * 8 + hi * 4);
      S0[g * 4 + 0] = a0.x; S0[g * 4 + 1] = a0.y; S0[g * 4 + 2] = a0.z; S0[g * 4 + 3] = a0.w;
      S1[g * 4 + 0] = a1.x; S1[g * 4 + 1] = a1.y; S1[g * 4 + 2] = a1.z; S1[g * 4 + 3] = a1.w;
    }

    // S^T = K · Q^T (swapped operands)
#pragma unroll
    for (int ks = 0; ks < 4; ++ks) {
      const int off0 = (ql * 128 + ks * 32 + hi * 16) ^ ((ql & 7) << 4);
      halfx8 kf0 = *(const halfx8*)((const char*)Klds + off0);
      S0 = __builtin_amdgcn_mfma_f32_32x32x16_f16(kf0, qf[ks], S0, 0, 0, 0);
      const int off1 = ((32 + ql) * 128 + ks * 32 + hi * 16) ^ ((ql & 7) << 4);
      halfx8 kf1 = *(const halfx8*)((const char*)Klds + off1);
      S1 = __builtin_amdgcn_mfma_f32_32x32x16_f16(kf1, qf[ks], S1, 0, 0, 0);
    }

    // tree max (depth ~5)
    float mx8[8];
#pragma unroll
    for (int i = 0; i < 8; ++i)
      mx8[i] = fmaxf(fmaxf(S0[i], S0[i + 8]), fmaxf(S1[i], S1[i + 8]));
#pragma unroll
    for (int i = 0; i < 4; ++i) mx8[i] = fmaxf(mx8[i], mx8[i + 4]);
    float mx = fmaxf(fmaxf(mx8[0], mx8[1]), fmaxf(mx8[2], mx8[3]));
    mx = fmaxf(mx, __shfl_xor(mx, 32));

    // T13 defer-max: rescale only when max grew past threshold (exp2 units)
    if (!__all(mx <= m_run + 8.0f)) {
      const float mn = fmaxf(m_run, mx);
      const float sc = exp2_fast(m_run - mn);
      m_run = mn;
      l_run *= sc;
#pragma unroll
      for (int i = 0; i < 16; ++i) { ctx0[i] *= sc; ctx1[i] *= sc; }
    }

    // P = exp2(S - m), tree sum
#pragma unroll
    for (int i = 0; i < 16; ++i) {
      S0[i] = exp2_fast(S0[i] - m_run);
      S1[i] = exp2_fast(S1[i] - m_run);
    }
    float sm8[8];
#pragma unroll
    for (int i = 0; i < 8; ++i)
      sm8[i] = (S0[i] + S0[i + 8]) + (S1[i] + S1[i + 8]);
#pragma unroll
    for (int i = 0; i < 4; ++i) sm8[i] += sm8[i + 4];
    float ps = (sm8[0] + sm8[1]) + (sm8[2] + sm8[3]);
    ps += __shfl_xor(ps, 32);
    l_run += ps;

    // pack P^T into PV B-fragments: cvt_pkrtz + permlane32_swap
    halfx8 pb[4];
#pragma unroll
    for (int sl = 0; sl < 4; ++sl) {
      const floatx16& P = (sl < 2) ? S0 : S1;
      const int rA = (sl & 1) * 8;
      unsigned wa = __builtin_bit_cast(unsigned, __builtin_amdgcn_cvt_pkrtz(P[rA + 0], P[rA + 1]));
      unsigned wb = __builtin_bit_cast(unsigned, __builtin_amdgcn_cvt_pkrtz(P[rA + 2], P[rA + 3]));
      unsigned wc = __builtin_bit_cast(unsigned, __builtin_amdgcn_cvt_pkrtz(P[rA + 4], P[rA + 5]));
      unsigned wd = __builtin_bit_cast(unsigned, __builtin_amdgcn_cvt_pkrtz(P[rA + 6], P[rA + 7]));
      uintx2 u1 = __builtin_amdgcn_permlane32_swap(wa, wc, false, false);
      uintx2 u2 = __builtin_amdgcn_permlane32_swap(wb, wd, false, false);
      uintx4 u;
      u[0] = u1[0]; u[1] = u2[0]; u[2] = u1[1]; u[3] = u2[1];
      pb[sl] = __builtin_bit_cast(halfx8, u);
    }

    // ctx^T += V^T · P^T
#pragma unroll
    for (int sl = 0; sl < 4; ++sl) {
      const int off0 = (ql * 128 + sl * 32 + hi * 16) ^ ((ql & 7) << 4);
      halfx8 vf0 = *(const halfx8*)((const char*)Vlds + off0);
      ctx0 = __builtin_amdgcn_mfma_f32_32x32x16_f16(vf0, pb[sl], ctx0, 0, 0, 0);
      const int off1 = ((32 + ql) * 128 + sl * 32 + hi * 16) ^ ((ql & 7) << 4);
      halfx8 vf1 = *(const halfx8*)((const char*)Vlds + off1);
      ctx1 = __builtin_amdgcn_mfma_f32_32x32x16_f16(vf1, pb[sl], ctx1, 0, 0, 0);
    }
  }

  // ---- in-block combine of the two kv-halves ----
  __syncthreads();  // all KV LDS reads done; overlay O on KV space
  {
    float* Op = (float*)(smem + p * 16384);  // [64 q][64 dv], swz
    const int q_local = w * 32 + ql;
#pragma unroll
    for (int g = 0; g < 4; ++g) {
#pragma unroll
      for (int pr = 0; pr < 2; ++pr) {
        const int r = g * 4 + pr * 2;
        const int dv0 = pr * 2 + 8 * g + 4 * hi;
        const int off0 = (q_local * 256 + dv0 * 4) ^ ((q_local & 7) << 4);
        *(float2*)((char*)Op + off0) = make_float2(ctx0[r], ctx0[r + 1]);
        const int off1 = (q_local * 256 + (dv0 + 32) * 4) ^ ((q_local & 7) << 4);
        *(float2*)((char*)Op + off1) = make_float2(ctx1[r], ctx1[r + 1]);
      }
    }
    if (hi == 0) {
      mlds[p * 128 + q_local] = m_run;
      mlds[p * 128 + 64 + q_local] = l_run;
    }
  }
  __syncthreads();

#pragma unroll
  for (int it = 0; it < 4; ++it) {
    const int idx = it * 256 + tid;
    const int q = idx >> 4, c4 = idx & 15;
    const int off = (q * 256 + c4 * 16) ^ ((q & 7) << 4);
    float4 o0 = *(const float4*)(smem + off);
    float4 o1 = *(const float4*)(smem + 16384 + off);
    const float m0 = mlds[q], l0 = mlds[64 + q];
    const float m1 = mlds[128 + q], l1 = mlds[192 + q];
    const float mm = fmaxf(m0, m1);
    float w0 = exp2_fast(m0 - mm), w1 = exp2_fast(m1 - mm);
    const int qglob = qt * 64 + q;
    const float inv = (hmask[b * kLD + qglob] ? 0.0f : 1.0f) / (l0 * w0 + l1 * w1);
    w0 *= inv; w1 *= inv;
    float4 o;
    o.x = o0.x * w0 + o1.x * w1;
    o.y = o0.y * w0 + o1.y * w1;
    o.z = o0.z * w0 + o1.z * w1;
    o.w = o0.w * w0 + o1.w * w1;
    *(float4*)(out + (((size_t)(b * kLD + qglob)) << 10) + h * 64 + c4 * 4) = o;
  }
}

// ---------------------------------------------------------------------------
extern "C" void kernel_launch(void* const* d_in, const int* in_sizes, int n_in,
                              void* d_out, int out_size, void* d_ws, size_t ws_size,
                              hipStream_t stream)
{
  const float* hs   = (const float*)d_in[0];
  const float* ehs  = (const float*)d_in[1];
  const int*   am   = (const int*)d_in[2];
  const int*   hm   = (const int*)d_in[3];
  const float* Wq   = (const float*)d_in[4];
  const float* bq   = (const float*)d_in[5];
  const float* Wk   = (const float*)d_in[6];
  const float* bk   = (const float*)d_in[7];
  const float* Wv   = (const float*)d_in[8];
  const float* bv   = (const float*)d_in[9];
  float* out = (float*)d_out;

  char* ws = (char*)d_ws;
  half_t* xdec_h = (half_t*)(ws);
  half_t* xenc_h = (half_t*)(ws + (8ull << 20));
  half_t* wq_h   = (half_t*)(ws + (16ull << 20));
  half_t* wk_h   = (half_t*)(ws + (18ull << 20));
  half_t* wv_h   = (half_t*)(ws + (20ull << 20));
  half_t* q_buf  = (half_t*)(ws + (22ull << 20));
  half_t* k_buf  = (half_t*)(ws + (30ull << 20));
  half_t* vt_buf = (half_t*)(ws + (38ull << 20));
  float*  maskf  = (float*)(ws + (46ull << 20));

  convert_all<<<11268, 256, 0, stream>>>(hs, ehs, Wq, Wk, Wv, am,
                                         xdec_h, xenc_h, wq_h, wk_h, wv_h, maskf);
  qkv_gemm<<<dim3(32, 8, 3), 256, 0, stream>>>(xdec_h, xenc_h, wq_h, wk_h, wv_h,
                                               bq, bk, bv, q_buf, k_buf, vt_buf);
  attn_kernel<<<1024, 256, 0, stream>>>(q_buf, k_buf, vt_buf, maskf, hm, out);
}